// Round 9
// baseline (1023.053 us; speedup 1.0000x reference)
//
#include <hip/hip_runtime.h>
#include <math.h>

// Exactness: the FPS argmax chain and the knn/ball-query comparisons must be
// bitwise identical to the numpy reference. Disable FMA contraction globally;
// use explicit fmaf() where fusion is wanted (non-comparison math).
#pragma clang fp contract(off)

typedef float v2f __attribute__((ext_vector_type(2)));

#define RLX __ATOMIC_RELAXED
#define AG  __HIP_MEMORY_SCOPE_AGENT

// Self-validating slot: one 8B relaxed device-scope atomic = (tag<<32)|payload.
// Per-location atomic coherence is guaranteed across XCDs; no fences.
// Round-8 lesson: these stores go to the COHERENT POINT (HBM latency ~900cy),
// and the pre-barrier vmcnt(0) drain puts that on FPS's serial path if issued
// every iteration -> batch them (48 slots by 48 lanes, once per 16 iters).
// Tags: bit30 set, bit31 clear -> never matches 0xAA.. poison, so no zeroing.
__device__ __forceinline__ void slot_store(unsigned long long* p,
                                           unsigned tag, unsigned payload) {
    __hip_atomic_store(p, ((unsigned long long)tag << 32) | payload, RLX, AG);
}
__device__ __forceinline__ unsigned slot_poll(const unsigned long long* p,
                                              unsigned tag) {
    unsigned long long v = __hip_atomic_load(p, RLX, AG);
    while ((unsigned)(v >> 32) != tag) {
        __builtin_amdgcn_s_sleep(8);
        v = __hip_atomic_load(p, RLX, AG);
    }
    return (unsigned)v;
}
#define TAG(i) (((unsigned)(i)) | 0x40000000u)

// ---------------------------------------------------------------------------
// prep: point norms (exact ((x*x+y*y)+z*z) order) + weight transposes
// ---------------------------------------------------------------------------
__global__ __launch_bounds__(256) void prep_kernel(
    const float* __restrict__ xyz, const float* __restrict__ w0,
    const float* __restrict__ w1, const float* __restrict__ w2,
    float* __restrict__ norms, float* __restrict__ W0T,
    float* __restrict__ W1T, float* __restrict__ W2c)
{
    int t = blockIdx.x * 256 + threadIdx.x;
    if (t < 16384) {
        float x = xyz[t*3+0], y = xyz[t*3+1], z = xyz[t*3+2];
        norms[t] = (x*x + y*y) + z*z;          // matches np.sum(a*a,-1) order
        int c = t >> 7, k = t & 127;
        W1T[c*128 + k] = w1[k*128 + c];
    }
    if (t < 2432) { int c = t / 19, i = t - c*19; W0T[t] = w0[i*128 + c]; }
    if (t < 128)  { W2c[t] = w2[t*256]; }
}

// ---------------------------------------------------------------------------
// DPP helpers (butterfly network validated bit-exact rounds 2-8):
// 0xB1=xor1, 0x4E=xor2, 0x141=row_half_mirror (xor4 once quad-uniform),
// 0x140=row_mirror (xor8 once 8-uniform), 0x142/0x143=row_bcast15/31
// (complete a 64-lane max/min; idempotent-op safe -> lane 63 holds result).
// ds_swizzle 0x401F = xor16 within each 32-lane half.
// ---------------------------------------------------------------------------
template<int CTRL>
__device__ __forceinline__ float dpp_f(float x) {
    int i = __float_as_int(x);
    return __int_as_float(__builtin_amdgcn_update_dpp(i, i, CTRL, 0xF, 0xF, false));
}
template<int CTRL>
__device__ __forceinline__ unsigned dpp_u(unsigned x) {
    int i = (int)x;
    return (unsigned)__builtin_amdgcn_update_dpp(i, i, CTRL, 0xF, 0xF, false);
}
template<int CTRL>
__device__ __forceinline__ unsigned long long dpp_u64(unsigned long long k) {
    int lo = (int)(unsigned int)k;
    int hi = (int)(unsigned int)(k >> 32);
    int plo = __builtin_amdgcn_update_dpp(lo, lo, CTRL, 0xF, 0xF, false);
    int phi = __builtin_amdgcn_update_dpp(hi, hi, CTRL, 0xF, 0xF, false);
    return ((unsigned long long)(unsigned int)phi << 32) | (unsigned int)plo;
}
__device__ __forceinline__ float swz16_f(float x) {
    return __int_as_float(__builtin_amdgcn_ds_swizzle(__float_as_int(x), 0x401F));
}
__device__ __forceinline__ unsigned swz16_u(unsigned x) {
    return (unsigned)__builtin_amdgcn_ds_swizzle((int)x, 0x401F);
}
template<int CTRL>
__device__ __forceinline__ unsigned long long min_u64_dpp(unsigned long long k) {
    unsigned long long p = dpp_u64<CTRL>(k);
    return p < k ? p : k;
}

// ---------------------------------------------------------------------------
// MEGA kernel, role-split, pipelined via tagged slots:
//   blocks 0..3       : FPS (round-7 loop; publishes selections in batches of
//                       16 via wave-0 lanes 0-47 -> one HBM-store drain per
//                       16 iterations instead of per-iteration)
//   blocks 4..2051    : KDE (publishes invden as tagged slots)
//   blocks 2052..2563 : KNN (1 wave/query, register-resident lex-exclusion,
//                       polls its query's 3 coord slots; publishes 32 idx slots)
//   blocks 2564..2819 : MLP+final (polls Q/knn/invden slots; writes out2)
// Producers precede consumers in dispatch order; no producer needs a consumer.
// ---------------------------------------------------------------------------
__global__ __launch_bounds__(512) void mega_kernel(
    const float* __restrict__ xyz, const float* __restrict__ feat,
    const float* __restrict__ norms,
    const float* __restrict__ W0T, const float* __restrict__ W1T,
    const float* __restrict__ W2c, const float* __restrict__ wwn,
    const float* __restrict__ wnl0, const float* __restrict__ wnl1,
    const float* __restrict__ wnp,
    float* __restrict__ new_xyz, float* __restrict__ out2,
    unsigned long long* __restrict__ nxs,    // 12288 slots: new_xyz coords
    unsigned long long* __restrict__ invs,   // 16384 slots: invden
    unsigned long long* __restrict__ knns)   // 131072 slots: knn indices
{
    __shared__ float4 pts[4096];                 // 64KB
    __shared__ float  nxb[3072];                 // 12KB FPS output staging
    __shared__ unsigned long long swk[2][16];
    __shared__ float  s_pw[16][32];              // MLPF role
    int tid = threadIdx.x;
    int bx = blockIdx.x;

    if (bx < 4) {
        // ------------------------------ FPS ------------------------------
        int b = bx;
        const float* Xb = xyz + b*12288;
        for (int t = tid; t < 4096; t += 512)
            pts[t] = make_float4(Xb[t*3+0], Xb[t*3+1], Xb[t*3+2], 0.0f);
        __syncthreads();
        float4 P[8];
#pragma unroll
        for (int k = 0; k < 8; ++k) P[k] = pts[k*512 + tid];
        v2f Xp[4], Yp[4], Zp[4], md2[4];
#pragma unroll
        for (int k = 0; k < 4; ++k) {
            Xp[k].x = P[k].x;  Xp[k].y = P[k+4].x;
            Yp[k].x = P[k].y;  Yp[k].y = P[k+4].y;
            Zp[k].x = P[k].z;  Zp[k].y = P[k+4].z;
            md2[k].x = INFINITY; md2[k].y = INFINITY;
        }
        float cx = pts[0].x, cy = pts[0].y, cz = pts[0].z;
        if (tid == 0) { nxb[0] = cx; nxb[1] = cy; nxb[2] = cz; }
        unsigned long long* nxsb = nxs + b*3072;
        int buf = 0;
        for (int it = 1; it < 1024; ++it) {
            // batched publish: selections it-16..it-1 (48 slots, 48 lanes of
            // wave 0, parallel stores -> one drain per 16 iters). nxb was
            // written by tid0 (same wave): wave-internal DS order suffices.
            if ((it & 15) == 0 && tid < 48) {
                int s = (it - 16)*3 + tid;
                unsigned g = (unsigned)(b*3072 + s);
                slot_store(nxsb + s, TAG(g), __float_as_uint(nxb[s]));
            }
            v2f cx2, cy2, cz2;
            cx2.x = cx; cx2.y = cx;
            cy2.x = cy; cy2.y = cy;
            cz2.x = cz; cz2.y = cz;
#pragma unroll
            for (int k = 0; k < 4; ++k) {
                v2f dx = Xp[k] - cx2, dy = Yp[k] - cy2, dz = Zp[k] - cz2;
                v2f dd = (dx*dx + dy*dy) + dz*dz;   // unfused (contract off)
                md2[k].x = fminf(md2[k].x, dd.x);
                md2[k].y = fminf(md2[k].y, dd.y);
            }
            // local argmax in ascending p order (p = j*512 + tid), strict >
            float bv = md2[0].x; int bj = 0;
            if (md2[1].x > bv) { bv = md2[1].x; bj = 1; }
            if (md2[2].x > bv) { bv = md2[2].x; bj = 2; }
            if (md2[3].x > bv) { bv = md2[3].x; bj = 3; }
            if (md2[0].y > bv) { bv = md2[0].y; bj = 4; }
            if (md2[1].y > bv) { bv = md2[1].y; bj = 5; }
            if (md2[2].y > bv) { bv = md2[2].y; bj = 6; }
            if (md2[3].y > bv) { bv = md2[3].y; bj = 7; }
            unsigned bp = (unsigned)(bj*512 + tid);
            // per-32-lane float max (1 inst/step, DPP folds into v_max_f32)
            float M = bv;
            M = fmaxf(M, dpp_f<0xB1>(M));
            M = fmaxf(M, dpp_f<0x4E>(M));
            M = fmaxf(M, dpp_f<0x141>(M));
            M = fmaxf(M, dpp_f<0x140>(M));
            M = fmaxf(M, swz16_f(M));
            // index: min p among lanes achieving M (numpy first-index)
            unsigned q = (bv == M) ? bp : 0xFFFFFFFFu;
            unsigned t0;
            t0 = dpp_u<0xB1>(q);  q = t0 < q ? t0 : q;
            t0 = dpp_u<0x4E>(q);  q = t0 < q ? t0 : q;
            t0 = dpp_u<0x141>(q); q = t0 < q ? t0 : q;
            t0 = dpp_u<0x140>(q); q = t0 < q ? t0 : q;
            t0 = swz16_u(q);      q = t0 < q ? t0 : q;
            if ((tid & 31) == 0)
                swk[buf][tid >> 5] =
                    ((unsigned long long)__float_as_uint(M) << 32) | (unsigned)(~q);
            __syncthreads();
            unsigned long long key = swk[buf][tid & 15];
            { unsigned long long o = dpp_u64<0xB1>(key);  if (o > key) key = o; }
            { unsigned long long o = dpp_u64<0x4E>(key);  if (o > key) key = o; }
            { unsigned long long o = dpp_u64<0x141>(key); if (o > key) key = o; }
            { unsigned long long o = dpp_u64<0x140>(key); if (o > key) key = o; }
            int fp = (int)(~(unsigned int)key);
            float4 c = pts[fp];              // broadcast read
            cx = c.x; cy = c.y; cz = c.z;
            if (tid == 0) { nxb[it*3+0] = cx; nxb[it*3+1] = cy; nxb[it*3+2] = cz; }
            buf ^= 1;
        }
        // final batch: selections 1008..1023 (nxb written by tid0, same wave)
        if (tid < 48) {
            int s = 3024 + tid;
            unsigned g = (unsigned)(b*3072 + s);
            slot_store(nxsb + s, TAG(g), __float_as_uint(nxb[s]));
        }
        __syncthreads();
        float* NX = new_xyz + b*3072;
        for (int t = tid; t < 3072; t += 512) NX[t] = nxb[t];
    } else if (bx < 2052) {
        // ------------------------------ KDE ------------------------------
        // In-ball count ~17 << KDE_K=128, so the reference's top-128 +
        // padding + correction reduces exactly to the mean of mvn over all
        // in-ball neighbors. Membership test uses the pdist2 expansion
        // formula (unfused) to match the reference set bitwise.
        int idx = bx - 4;
        int b = idx >> 9;                    // 512 blocks per batch
        int wave = tid >> 6, lane = tid & 63;
        int i_local = ((idx & 511) << 3) + wave;
        const float* Xb = xyz + b*12288;
        const float* Nb = norms + b*4096;
        for (int t = tid; t < 4096; t += 512)
            pts[t] = make_float4(Xb[t*3+0], Xb[t*3+1], Xb[t*3+2], Nb[t]);
        __syncthreads();
        float4 c = pts[i_local];
        const float Rv    = sqrtf(0.05f);
        const float inv_s = 1.0f / (Rv*Rv);
        const float K1    = -3.0f*logf(Rv) - 1.5f*logf(2.0f*3.1415926f);
        float csum = 0.0f; int cnt = 0;
        for (int j = lane; j < 4096; j += 64) {
            float4 p = pts[j];
            float dot = (c.x*p.x + c.y*p.y) + c.z*p.z;
            float t2 = 2.0f * dot;
            float d2 = (c.w + p.w) - t2;
            if (d2 < 0.01f) {                // 0.01f == float32(0.1*0.1)
                float gx = p.x - c.x, gy = p.y - c.y, gz = p.z - c.z;
                float dd = (gx*gx + gy*gy) + gz*gz;
                csum += expf(-0.5f * (dd * inv_s) + K1);
                cnt  += 1;
            }
        }
#pragma unroll
        for (int m = 1; m < 64; m <<= 1) {
            csum += __shfl_xor(csum, m, 64);
            cnt  += __shfl_xor(cnt,  m, 64);
        }
        if (lane == 0) {
            float den = csum / (float)cnt;
            int gi = b*4096 + i_local;
            slot_store(&invs[gi], TAG(gi), __float_as_uint(1.0f / den));
        }
    } else if (bx < 2564) {
        // ------------------------------ KNN ------------------------------
        // One wave per query; 64 order-isomorphic u32 keys/lane in registers
        // (sign-transformed d2 bits). Round r: lex-min (ord, j) among
        // candidates lex-greater than the previous winner == stable top_k
        // (validated end-to-end rounds 4/8). Reduce = DPP u64-min network;
        // winner broadcast via readlane 63.
        int qg = (bx - 2052)*8 + (tid >> 6);     // 0..4095 = b*1024 + q
        int lane = tid & 63;
        int b = qg >> 10;
        float qx, qy, qz;
        {
            unsigned g = (unsigned)(qg*3);
            qx = __uint_as_float(slot_poll(&nxs[qg*3+0], TAG(g+0)));
            qy = __uint_as_float(slot_poll(&nxs[qg*3+1], TAG(g+1)));
            qz = __uint_as_float(slot_poll(&nxs[qg*3+2], TAG(g+2)));
        }
        float nq = (qx*qx + qy*qy) + qz*qz;
        const float* Xb = xyz + b*12288;
        unsigned ord[64];
#pragma unroll
        for (int k = 0; k < 64; ++k) {
            int j = (lane << 6) + k;
            float x = Xb[j*3+0], y = Xb[j*3+1], z = Xb[j*3+2];
            float nj = (x*x + y*y) + z*z;          // == norms[j] bitwise
            float dot = (qx*x + qy*y) + qz*z;
            float t2 = 2.0f*dot;
            float d = (nq + nj) - t2;
            unsigned u = __float_as_uint(d);
            unsigned m = ((unsigned)((int)u >> 31)) | 0x80000000u;
            ord[k] = u ^ m;
        }
        unsigned w_ord = 0u; int w_j = -1;
        for (int r = 0; r < 32; ++r) {
            int t = w_j - (lane << 6);             // j > w_j  <=>  k > t
            unsigned best = 0xFFFFFFFFu; int bk = 64;
#pragma unroll
            for (int k = 0; k < 64; ++k) {
                unsigned o = ord[k];
                bool valid = (o > w_ord) || ((o == w_ord) && (k > t));
                bool take = valid && (o < best);   // asc k => first-idx tie-break
                best = take ? o : best;
                bk   = take ? k : bk;
            }
            unsigned long long key =
                ((unsigned long long)best << 32) | (unsigned)((lane << 6) + bk);
            key = min_u64_dpp<0xB1>(key);
            key = min_u64_dpp<0x4E>(key);
            key = min_u64_dpp<0x141>(key);
            key = min_u64_dpp<0x140>(key);
            key = min_u64_dpp<0x142>(key);
            key = min_u64_dpp<0x143>(key);         // lane 63 = wave min
            w_j   = __builtin_amdgcn_readlane((int)(unsigned)key, 63);
            w_ord = (unsigned)__builtin_amdgcn_readlane((int)(unsigned)(key >> 32), 63);
            if (lane == 0) {
                int gi = qg*32 + r;
                slot_store(&knns[gi], TAG(gi), (unsigned)w_j);
            }
        }
    } else {
        // --------------------------- MLP + final ---------------------------
        int blk = bx - 2564;                       // 0..255, 16 points each
        int row = blk*512 + tid;                   // global row = pg*32 + k
        int k  = row & 31;
        int pg = row >> 5;
        int b  = row >> 15;
        float Q0, Q1, Q2;
        {
            unsigned g = (unsigned)(pg*3);
            Q0 = __uint_as_float(slot_poll(&nxs[pg*3+0], TAG(g+0)));
            Q1 = __uint_as_float(slot_poll(&nxs[pg*3+1], TAG(g+1)));
            Q2 = __uint_as_float(slot_poll(&nxs[pg*3+2], TAG(g+2)));
        }
        int j = (int)slot_poll(&knns[row], TAG(row));
        float gd;
        {
            int gi = b*4096 + j;
            gd = __uint_as_float(slot_poll(&invs[gi], TAG(gi)));
        }
        const float* Xb = xyz + b*12288;
        float in[19];
        in[0] = Xb[j*3+0] - Q0;
        in[1] = Xb[j*3+1] - Q1;
        in[2] = Xb[j*3+2] - Q2;
        const float4* F = (const float4*)(feat + (size_t)(b*4096 + j)*16);
        float4 f0 = F[0], f1 = F[1], f2 = F[2], f3 = F[3];
        in[3]=f0.x; in[4]=f0.y; in[5]=f0.z; in[6]=f0.w;
        in[7]=f1.x; in[8]=f1.y; in[9]=f1.z; in[10]=f1.w;
        in[11]=f2.x; in[12]=f2.y; in[13]=f2.z; in[14]=f2.w;
        in[15]=f3.x; in[16]=f3.y; in[17]=f3.z; in[18]=f3.w;

        // density scale: gd / max_k(gd), then 1->16->1 relu MLP
        float mx = gd;
#pragma unroll
        for (int m = 1; m < 32; m <<= 1) mx = fmaxf(mx, __shfl_xor(mx, m, 64));
        float dsc = gd / mx;
        float sacc = 0.0f;
#pragma unroll
        for (int t = 0; t < 16; ++t)
            sacc = fmaf(fmaxf(dsc * wnl0[t], 0.0f), wnl1[t], sacc);
        float ds = fmaxf(sacc, 0.0f);

        // L0: 19 -> 128 (fully unrolled so h1 stays in registers)
        float h1[128];
#pragma unroll
        for (int c = 0; c < 128; ++c) {
            const float* w = W0T + c*19;
            float a = in[0]*w[0];
#pragma unroll
            for (int i = 1; i < 19; ++i) a = fmaf(in[i], w[i], a);
            h1[c] = fmaxf(a, 0.0f);
        }
        // L1 + L2(col 0)
        float acc0 = 0.0f;
        for (int c2 = 0; c2 < 128; ++c2) {
            const float* w = W1T + c2*128;
            float a0 = 0.0f, a1 = 0.0f, a2 = 0.0f, a3 = 0.0f;
#pragma unroll
            for (int kk = 0; kk < 128; kk += 4) {
                a0 = fmaf(h1[kk+0], w[kk+0], a0);
                a1 = fmaf(h1[kk+1], w[kk+1], a1);
                a2 = fmaf(h1[kk+2], w[kk+2], a2);
                a3 = fmaf(h1[kk+3], w[kk+3], a3);
            }
            float a = (a0+a1) + (a2+a3);
            acc0 = fmaf(fmaxf(a, 0.0f), W2c[c2], acc0);
        }
        float h0 = fmaxf(acc0, 0.0f);
        float s = h0 * ds;

        // weight net (3->32) + reduce over k (32 lanes of half-wave)
        float gx = in[0], gy = in[1], gz = in[2];
        int pl = tid >> 5;                         // 0..15 local point
#pragma unroll
        for (int w = 0; w < 32; ++w) {
            float a = gx * wwn[w];
            a = fmaf(gy, wwn[32+w], a);
            a = fmaf(gz, wwn[64+w], a);
            float part = s * fmaxf(a, 0.0f);
#pragma unroll
            for (int m = 1; m < 32; m <<= 1) part += __shfl_xor(part, m, 64);
            if (k == 0) s_pw[pl][w] = part;
        }
        __syncthreads();
        // final: out[b,p,f] = relu( sum_w pw[w] * wnp[w,f] )
        int f = tid & 255;
        int half = tid >> 8;                       // 0/1 -> points 0-7 / 8-15
        int pg0 = blk*16;
#pragma unroll
        for (int pt = 0; pt < 8; ++pt) {
            int p = half*8 + pt;
            float a = 0.0f;
#pragma unroll
            for (int w = 0; w < 32; ++w)
                a = fmaf(s_pw[p][w], wnp[w*256+f], a);
            out2[(pg0 + p)*256 + f] = fmaxf(a, 0.0f);
        }
    }
}

// ---------------------------------------------------------------------------
extern "C" void kernel_launch(void* const* d_in, const int* in_sizes, int n_in,
                              void* d_out, int out_size, void* d_ws, size_t ws_size,
                              hipStream_t stream) {
    const float* xyz  = (const float*)d_in[0];
    const float* feat = (const float*)d_in[1];
    const float* w0   = (const float*)d_in[2];
    const float* w1   = (const float*)d_in[3];
    const float* w2   = (const float*)d_in[4];
    const float* wwn  = (const float*)d_in[5];
    const float* wnl0 = (const float*)d_in[6];
    const float* wnl1 = (const float*)d_in[7];
    const float* wnp  = (const float*)d_in[8];

    float* out_all  = (float*)d_out;
    float* new_xyz  = out_all;            // 4*1024*3 = 12288 floats
    float* out2     = out_all + 12288;    // 4*1024*256 floats

    char* ws = (char*)d_ws;
    float* norms = (float*)(ws + 0);                      // 65536 B
    float* W0T   = (float*)(ws + 65536);                  // 9728 B
    float* W1T   = (float*)(ws + 75264);                  // 65536 B
    float* W2c   = (float*)(ws + 140800);                 // 512 B
    unsigned long long* nxs  = (unsigned long long*)(ws + 141312);  // 98304 B
    unsigned long long* invs = (unsigned long long*)(ws + 239616);  // 131072 B
    unsigned long long* knns = (unsigned long long*)(ws + 370688);  // 1048576 B
    // total 1419264 B; poison-tagged slots need no zeroing (see slot_store).

    prep_kernel<<<64, 256, 0, stream>>>(xyz, w0, w1, w2, norms, W0T, W1T, W2c);
    mega_kernel<<<2820, 512, 0, stream>>>(xyz, feat, norms, W0T, W1T, W2c,
                                          wwn, wnl0, wnl1, wnp,
                                          new_xyz, out2, nxs, invs, knns);
}

// Round 10
// 1021.653 us; speedup vs baseline: 1.0014x; 1.0014x over previous
//
#include <hip/hip_runtime.h>
#include <math.h>

// Exactness: the FPS argmax chain and the knn/ball-query comparisons must be
// bitwise identical to the numpy reference. Disable FMA contraction globally;
// use explicit fmaf() where fusion is wanted (non-comparison math).
#pragma clang fp contract(off)

typedef float v2f __attribute__((ext_vector_type(2)));

#define RLX __ATOMIC_RELAXED
#define AG  __HIP_MEMORY_SCOPE_AGENT

// Self-validating slot: one 8B relaxed device-scope atomic = (tag<<32)|payload.
// Per-location atomic coherence is guaranteed across XCDs; no fences.
// Tags: bit30 set, bit31 clear -> never matches 0xAA.. poison, so no zeroing.
__device__ __forceinline__ void slot_store(unsigned long long* p,
                                           unsigned tag, unsigned payload) {
    __hip_atomic_store(p, ((unsigned long long)tag << 32) | payload, RLX, AG);
}
__device__ __forceinline__ unsigned slot_poll(const unsigned long long* p,
                                              unsigned tag) {
    unsigned long long v = __hip_atomic_load(p, RLX, AG);
    while ((unsigned)(v >> 32) != tag) {
        __builtin_amdgcn_s_sleep(8);
        v = __hip_atomic_load(p, RLX, AG);
    }
    return (unsigned)v;
}
#define TAG(i) (((unsigned)(i)) | 0x40000000u)

// ---------------------------------------------------------------------------
// prep: point norms (exact ((x*x+y*y)+z*z) order) + weight transposes
// ---------------------------------------------------------------------------
__global__ __launch_bounds__(256) void prep_kernel(
    const float* __restrict__ xyz, const float* __restrict__ w0,
    const float* __restrict__ w1, const float* __restrict__ w2,
    float* __restrict__ norms, float* __restrict__ W0T,
    float* __restrict__ W1T, float* __restrict__ W2c)
{
    int t = blockIdx.x * 256 + threadIdx.x;
    if (t < 16384) {
        float x = xyz[t*3+0], y = xyz[t*3+1], z = xyz[t*3+2];
        norms[t] = (x*x + y*y) + z*z;          // matches np.sum(a*a,-1) order
        int c = t >> 7, k = t & 127;
        W1T[c*128 + k] = w1[k*128 + c];
    }
    if (t < 2432) { int c = t / 19, i = t - c*19; W0T[t] = w0[i*128 + c]; }
    if (t < 128)  { W2c[t] = w2[t*256]; }
}

// ---------------------------------------------------------------------------
// DPP helpers (butterfly network validated bit-exact rounds 2-9):
// 0xB1=xor1, 0x4E=xor2, 0x141=row_half_mirror (xor4 once quad-uniform),
// 0x140=row_mirror (xor8 once 8-uniform), 0x142/0x143=row_bcast15/31
// (complete a 64-lane max/min; idempotent-op safe -> lane 63 holds result).
// ds_swizzle 0x401F = xor16 within each 32-lane half.
// ---------------------------------------------------------------------------
template<int CTRL>
__device__ __forceinline__ float dpp_f(float x) {
    int i = __float_as_int(x);
    return __int_as_float(__builtin_amdgcn_update_dpp(i, i, CTRL, 0xF, 0xF, false));
}
template<int CTRL>
__device__ __forceinline__ unsigned dpp_u(unsigned x) {
    int i = (int)x;
    return (unsigned)__builtin_amdgcn_update_dpp(i, i, CTRL, 0xF, 0xF, false);
}
template<int CTRL>
__device__ __forceinline__ unsigned long long dpp_u64(unsigned long long k) {
    int lo = (int)(unsigned int)k;
    int hi = (int)(unsigned int)(k >> 32);
    int plo = __builtin_amdgcn_update_dpp(lo, lo, CTRL, 0xF, 0xF, false);
    int phi = __builtin_amdgcn_update_dpp(hi, hi, CTRL, 0xF, 0xF, false);
    return ((unsigned long long)(unsigned int)phi << 32) | (unsigned int)plo;
}
__device__ __forceinline__ float swz16_f(float x) {
    return __int_as_float(__builtin_amdgcn_ds_swizzle(__float_as_int(x), 0x401F));
}
__device__ __forceinline__ unsigned swz16_u(unsigned x) {
    return (unsigned)__builtin_amdgcn_ds_swizzle((int)x, 0x401F);
}
template<int CTRL>
__device__ __forceinline__ unsigned long long min_u64_dpp(unsigned long long k) {
    unsigned long long p = dpp_u64<CTRL>(k);
    return p < k ? p : k;
}

// ---------------------------------------------------------------------------
// MEGA kernel, role-split, pipelined via tagged slots.
// ROUND-10 CHANGE (one variable): launch with 8KB dynamic LDS so per-block
// LDS = 80384+8192 = 88576 B > 80KB -> exactly ONE block per CU. Round 9's
// diagnosis: with 2 blocks/CU, retiring co-residents get backfilled by
// spinning KNN/MLPF blocks that steal issue slots from the latency-critical
// FPS waves for ~850us (standalone FPS=703us vs in-mega ~978us). Dedicated
// CUs restore FPS isolation while consumers overlap on the other 252 CUs.
//   blocks 0..3       : FPS (publishes selections in batches of 16)
//   blocks 4..2051    : KDE (publishes invden as tagged slots)
//   blocks 2052..2563 : KNN (1 wave/query, register-resident lex-exclusion)
//   blocks 2564..2819 : MLP+final (polls Q/knn/invden slots; writes out2)
// Producers precede consumers in dispatch order; no producer needs a consumer.
// ---------------------------------------------------------------------------
extern __shared__ char lds_occupancy_pad[];   // never referenced; reserves LDS

__global__ __launch_bounds__(512) void mega_kernel(
    const float* __restrict__ xyz, const float* __restrict__ feat,
    const float* __restrict__ norms,
    const float* __restrict__ W0T, const float* __restrict__ W1T,
    const float* __restrict__ W2c, const float* __restrict__ wwn,
    const float* __restrict__ wnl0, const float* __restrict__ wnl1,
    const float* __restrict__ wnp,
    float* __restrict__ new_xyz, float* __restrict__ out2,
    unsigned long long* __restrict__ nxs,    // 12288 slots: new_xyz coords
    unsigned long long* __restrict__ invs,   // 16384 slots: invden
    unsigned long long* __restrict__ knns)   // 131072 slots: knn indices
{
    __shared__ float4 pts[4096];                 // 64KB
    __shared__ float  nxb[3072];                 // 12KB FPS output staging
    __shared__ unsigned long long swk[2][16];
    __shared__ float  s_pw[16][32];              // MLPF role
    int tid = threadIdx.x;
    int bx = blockIdx.x;

    if (bx < 4) {
        // ------------------------------ FPS ------------------------------
        int b = bx;
        const float* Xb = xyz + b*12288;
        for (int t = tid; t < 4096; t += 512)
            pts[t] = make_float4(Xb[t*3+0], Xb[t*3+1], Xb[t*3+2], 0.0f);
        __syncthreads();
        float4 P[8];
#pragma unroll
        for (int k = 0; k < 8; ++k) P[k] = pts[k*512 + tid];
        v2f Xp[4], Yp[4], Zp[4], md2[4];
#pragma unroll
        for (int k = 0; k < 4; ++k) {
            Xp[k].x = P[k].x;  Xp[k].y = P[k+4].x;
            Yp[k].x = P[k].y;  Yp[k].y = P[k+4].y;
            Zp[k].x = P[k].z;  Zp[k].y = P[k+4].z;
            md2[k].x = INFINITY; md2[k].y = INFINITY;
        }
        float cx = pts[0].x, cy = pts[0].y, cz = pts[0].z;
        if (tid == 0) { nxb[0] = cx; nxb[1] = cy; nxb[2] = cz; }
        unsigned long long* nxsb = nxs + b*3072;
        int buf = 0;
        for (int it = 1; it < 1024; ++it) {
            // batched publish: selections it-16..it-1 (48 slots, 48 lanes of
            // wave 0, parallel stores -> one drain per 16 iters). nxb was
            // written by tid0 (same wave): wave-internal DS order suffices.
            if ((it & 15) == 0 && tid < 48) {
                int s = (it - 16)*3 + tid;
                unsigned g = (unsigned)(b*3072 + s);
                slot_store(nxsb + s, TAG(g), __float_as_uint(nxb[s]));
            }
            v2f cx2, cy2, cz2;
            cx2.x = cx; cx2.y = cx;
            cy2.x = cy; cy2.y = cy;
            cz2.x = cz; cz2.y = cz;
#pragma unroll
            for (int k = 0; k < 4; ++k) {
                v2f dx = Xp[k] - cx2, dy = Yp[k] - cy2, dz = Zp[k] - cz2;
                v2f dd = (dx*dx + dy*dy) + dz*dz;   // unfused (contract off)
                md2[k].x = fminf(md2[k].x, dd.x);
                md2[k].y = fminf(md2[k].y, dd.y);
            }
            // local argmax in ascending p order (p = j*512 + tid), strict >
            float bv = md2[0].x; int bj = 0;
            if (md2[1].x > bv) { bv = md2[1].x; bj = 1; }
            if (md2[2].x > bv) { bv = md2[2].x; bj = 2; }
            if (md2[3].x > bv) { bv = md2[3].x; bj = 3; }
            if (md2[0].y > bv) { bv = md2[0].y; bj = 4; }
            if (md2[1].y > bv) { bv = md2[1].y; bj = 5; }
            if (md2[2].y > bv) { bv = md2[2].y; bj = 6; }
            if (md2[3].y > bv) { bv = md2[3].y; bj = 7; }
            unsigned bp = (unsigned)(bj*512 + tid);
            // per-32-lane float max (1 inst/step, DPP folds into v_max_f32)
            float M = bv;
            M = fmaxf(M, dpp_f<0xB1>(M));
            M = fmaxf(M, dpp_f<0x4E>(M));
            M = fmaxf(M, dpp_f<0x141>(M));
            M = fmaxf(M, dpp_f<0x140>(M));
            M = fmaxf(M, swz16_f(M));
            // index: min p among lanes achieving M (numpy first-index)
            unsigned q = (bv == M) ? bp : 0xFFFFFFFFu;
            unsigned t0;
            t0 = dpp_u<0xB1>(q);  q = t0 < q ? t0 : q;
            t0 = dpp_u<0x4E>(q);  q = t0 < q ? t0 : q;
            t0 = dpp_u<0x141>(q); q = t0 < q ? t0 : q;
            t0 = dpp_u<0x140>(q); q = t0 < q ? t0 : q;
            t0 = swz16_u(q);      q = t0 < q ? t0 : q;
            if ((tid & 31) == 0)
                swk[buf][tid >> 5] =
                    ((unsigned long long)__float_as_uint(M) << 32) | (unsigned)(~q);
            __syncthreads();
            unsigned long long key = swk[buf][tid & 15];
            { unsigned long long o = dpp_u64<0xB1>(key);  if (o > key) key = o; }
            { unsigned long long o = dpp_u64<0x4E>(key);  if (o > key) key = o; }
            { unsigned long long o = dpp_u64<0x141>(key); if (o > key) key = o; }
            { unsigned long long o = dpp_u64<0x140>(key); if (o > key) key = o; }
            int fp = (int)(~(unsigned int)key);
            float4 c = pts[fp];              // broadcast read
            cx = c.x; cy = c.y; cz = c.z;
            if (tid == 0) { nxb[it*3+0] = cx; nxb[it*3+1] = cy; nxb[it*3+2] = cz; }
            buf ^= 1;
        }
        // final batch: selections 1008..1023 (nxb written by tid0, same wave)
        if (tid < 48) {
            int s = 3024 + tid;
            unsigned g = (unsigned)(b*3072 + s);
            slot_store(nxsb + s, TAG(g), __float_as_uint(nxb[s]));
        }
        __syncthreads();
        float* NX = new_xyz + b*3072;
        for (int t = tid; t < 3072; t += 512) NX[t] = nxb[t];
    } else if (bx < 2052) {
        // ------------------------------ KDE ------------------------------
        // In-ball count ~17 << KDE_K=128, so the reference's top-128 +
        // padding + correction reduces exactly to the mean of mvn over all
        // in-ball neighbors. Membership test uses the pdist2 expansion
        // formula (unfused) to match the reference set bitwise.
        int idx = bx - 4;
        int b = idx >> 9;                    // 512 blocks per batch
        int wave = tid >> 6, lane = tid & 63;
        int i_local = ((idx & 511) << 3) + wave;
        const float* Xb = xyz + b*12288;
        const float* Nb = norms + b*4096;
        for (int t = tid; t < 4096; t += 512)
            pts[t] = make_float4(Xb[t*3+0], Xb[t*3+1], Xb[t*3+2], Nb[t]);
        __syncthreads();
        float4 c = pts[i_local];
        const float Rv    = sqrtf(0.05f);
        const float inv_s = 1.0f / (Rv*Rv);
        const float K1    = -3.0f*logf(Rv) - 1.5f*logf(2.0f*3.1415926f);
        float csum = 0.0f; int cnt = 0;
        for (int j = lane; j < 4096; j += 64) {
            float4 p = pts[j];
            float dot = (c.x*p.x + c.y*p.y) + c.z*p.z;
            float t2 = 2.0f * dot;
            float d2 = (c.w + p.w) - t2;
            if (d2 < 0.01f) {                // 0.01f == float32(0.1*0.1)
                float gx = p.x - c.x, gy = p.y - c.y, gz = p.z - c.z;
                float dd = (gx*gx + gy*gy) + gz*gz;
                csum += expf(-0.5f * (dd * inv_s) + K1);
                cnt  += 1;
            }
        }
#pragma unroll
        for (int m = 1; m < 64; m <<= 1) {
            csum += __shfl_xor(csum, m, 64);
            cnt  += __shfl_xor(cnt,  m, 64);
        }
        if (lane == 0) {
            float den = csum / (float)cnt;
            int gi = b*4096 + i_local;
            slot_store(&invs[gi], TAG(gi), __float_as_uint(1.0f / den));
        }
    } else if (bx < 2564) {
        // ------------------------------ KNN ------------------------------
        // One wave per query; 64 order-isomorphic u32 keys/lane in registers
        // (sign-transformed d2 bits). Round r: lex-min (ord, j) among
        // candidates lex-greater than the previous winner == stable top_k
        // (validated end-to-end rounds 4/8/9). Reduce = DPP u64-min network;
        // winner broadcast via readlane 63.
        int qg = (bx - 2052)*8 + (tid >> 6);     // 0..4095 = b*1024 + q
        int lane = tid & 63;
        int b = qg >> 10;
        float qx, qy, qz;
        {
            unsigned g = (unsigned)(qg*3);
            qx = __uint_as_float(slot_poll(&nxs[qg*3+0], TAG(g+0)));
            qy = __uint_as_float(slot_poll(&nxs[qg*3+1], TAG(g+1)));
            qz = __uint_as_float(slot_poll(&nxs[qg*3+2], TAG(g+2)));
        }
        float nq = (qx*qx + qy*qy) + qz*qz;
        const float* Xb = xyz + b*12288;
        unsigned ord[64];
#pragma unroll
        for (int k = 0; k < 64; ++k) {
            int j = (lane << 6) + k;
            float x = Xb[j*3+0], y = Xb[j*3+1], z = Xb[j*3+2];
            float nj = (x*x + y*y) + z*z;          // == norms[j] bitwise
            float dot = (qx*x + qy*y) + qz*z;
            float t2 = 2.0f*dot;
            float d = (nq + nj) - t2;
            unsigned u = __float_as_uint(d);
            unsigned m = ((unsigned)((int)u >> 31)) | 0x80000000u;
            ord[k] = u ^ m;
        }
        unsigned w_ord = 0u; int w_j = -1;
        for (int r = 0; r < 32; ++r) {
            int t = w_j - (lane << 6);             // j > w_j  <=>  k > t
            unsigned best = 0xFFFFFFFFu; int bk = 64;
#pragma unroll
            for (int k = 0; k < 64; ++k) {
                unsigned o = ord[k];
                bool valid = (o > w_ord) || ((o == w_ord) && (k > t));
                bool take = valid && (o < best);   // asc k => first-idx tie-break
                best = take ? o : best;
                bk   = take ? k : bk;
            }
            unsigned long long key =
                ((unsigned long long)best << 32) | (unsigned)((lane << 6) + bk);
            key = min_u64_dpp<0xB1>(key);
            key = min_u64_dpp<0x4E>(key);
            key = min_u64_dpp<0x141>(key);
            key = min_u64_dpp<0x140>(key);
            key = min_u64_dpp<0x142>(key);
            key = min_u64_dpp<0x143>(key);         // lane 63 = wave min
            w_j   = __builtin_amdgcn_readlane((int)(unsigned)key, 63);
            w_ord = (unsigned)__builtin_amdgcn_readlane((int)(unsigned)(key >> 32), 63);
            if (lane == 0) {
                int gi = qg*32 + r;
                slot_store(&knns[gi], TAG(gi), (unsigned)w_j);
            }
        }
    } else {
        // --------------------------- MLP + final ---------------------------
        int blk = bx - 2564;                       // 0..255, 16 points each
        int row = blk*512 + tid;                   // global row = pg*32 + k
        int k  = row & 31;
        int pg = row >> 5;
        int b  = row >> 15;
        float Q0, Q1, Q2;
        {
            unsigned g = (unsigned)(pg*3);
            Q0 = __uint_as_float(slot_poll(&nxs[pg*3+0], TAG(g+0)));
            Q1 = __uint_as_float(slot_poll(&nxs[pg*3+1], TAG(g+1)));
            Q2 = __uint_as_float(slot_poll(&nxs[pg*3+2], TAG(g+2)));
        }
        int j = (int)slot_poll(&knns[row], TAG(row));
        float gd;
        {
            int gi = b*4096 + j;
            gd = __uint_as_float(slot_poll(&invs[gi], TAG(gi)));
        }
        const float* Xb = xyz + b*12288;
        float in[19];
        in[0] = Xb[j*3+0] - Q0;
        in[1] = Xb[j*3+1] - Q1;
        in[2] = Xb[j*3+2] - Q2;
        const float4* F = (const float4*)(feat + (size_t)(b*4096 + j)*16);
        float4 f0 = F[0], f1 = F[1], f2 = F[2], f3 = F[3];
        in[3]=f0.x; in[4]=f0.y; in[5]=f0.z; in[6]=f0.w;
        in[7]=f1.x; in[8]=f1.y; in[9]=f1.z; in[10]=f1.w;
        in[11]=f2.x; in[12]=f2.y; in[13]=f2.z; in[14]=f2.w;
        in[15]=f3.x; in[16]=f3.y; in[17]=f3.z; in[18]=f3.w;

        // density scale: gd / max_k(gd), then 1->16->1 relu MLP
        float mx = gd;
#pragma unroll
        for (int m = 1; m < 32; m <<= 1) mx = fmaxf(mx, __shfl_xor(mx, m, 64));
        float dsc = gd / mx;
        float sacc = 0.0f;
#pragma unroll
        for (int t = 0; t < 16; ++t)
            sacc = fmaf(fmaxf(dsc * wnl0[t], 0.0f), wnl1[t], sacc);
        float ds = fmaxf(sacc, 0.0f);

        // L0: 19 -> 128 (fully unrolled so h1 stays in registers)
        float h1[128];
#pragma unroll
        for (int c = 0; c < 128; ++c) {
            const float* w = W0T + c*19;
            float a = in[0]*w[0];
#pragma unroll
            for (int i = 1; i < 19; ++i) a = fmaf(in[i], w[i], a);
            h1[c] = fmaxf(a, 0.0f);
        }
        // L1 + L2(col 0)
        float acc0 = 0.0f;
        for (int c2 = 0; c2 < 128; ++c2) {
            const float* w = W1T + c2*128;
            float a0 = 0.0f, a1 = 0.0f, a2 = 0.0f, a3 = 0.0f;
#pragma unroll
            for (int kk = 0; kk < 128; kk += 4) {
                a0 = fmaf(h1[kk+0], w[kk+0], a0);
                a1 = fmaf(h1[kk+1], w[kk+1], a1);
                a2 = fmaf(h1[kk+2], w[kk+2], a2);
                a3 = fmaf(h1[kk+3], w[kk+3], a3);
            }
            float a = (a0+a1) + (a2+a3);
            acc0 = fmaf(fmaxf(a, 0.0f), W2c[c2], acc0);
        }
        float h0 = fmaxf(acc0, 0.0f);
        float s = h0 * ds;

        // weight net (3->32) + reduce over k (32 lanes of half-wave)
        float gx = in[0], gy = in[1], gz = in[2];
        int pl = tid >> 5;                         // 0..15 local point
#pragma unroll
        for (int w = 0; w < 32; ++w) {
            float a = gx * wwn[w];
            a = fmaf(gy, wwn[32+w], a);
            a = fmaf(gz, wwn[64+w], a);
            float part = s * fmaxf(a, 0.0f);
#pragma unroll
            for (int m = 1; m < 32; m <<= 1) part += __shfl_xor(part, m, 64);
            if (k == 0) s_pw[pl][w] = part;
        }
        __syncthreads();
        // final: out[b,p,f] = relu( sum_w pw[w] * wnp[w,f] )
        int f = tid & 255;
        int half = tid >> 8;                       // 0/1 -> points 0-7 / 8-15
        int pg0 = blk*16;
#pragma unroll
        for (int pt = 0; pt < 8; ++pt) {
            int p = half*8 + pt;
            float a = 0.0f;
#pragma unroll
            for (int w = 0; w < 32; ++w)
                a = fmaf(s_pw[p][w], wnp[w*256+f], a);
            out2[(pg0 + p)*256 + f] = fmaxf(a, 0.0f);
        }
    }
}

// ---------------------------------------------------------------------------
extern "C" void kernel_launch(void* const* d_in, const int* in_sizes, int n_in,
                              void* d_out, int out_size, void* d_ws, size_t ws_size,
                              hipStream_t stream) {
    const float* xyz  = (const float*)d_in[0];
    const float* feat = (const float*)d_in[1];
    const float* w0   = (const float*)d_in[2];
    const float* w1   = (const float*)d_in[3];
    const float* w2   = (const float*)d_in[4];
    const float* wwn  = (const float*)d_in[5];
    const float* wnl0 = (const float*)d_in[6];
    const float* wnl1 = (const float*)d_in[7];
    const float* wnp  = (const float*)d_in[8];

    float* out_all  = (float*)d_out;
    float* new_xyz  = out_all;            // 4*1024*3 = 12288 floats
    float* out2     = out_all + 12288;    // 4*1024*256 floats

    char* ws = (char*)d_ws;
    float* norms = (float*)(ws + 0);                      // 65536 B
    float* W0T   = (float*)(ws + 65536);                  // 9728 B
    float* W1T   = (float*)(ws + 75264);                  // 65536 B
    float* W2c   = (float*)(ws + 140800);                 // 512 B
    unsigned long long* nxs  = (unsigned long long*)(ws + 141312);  // 98304 B
    unsigned long long* invs = (unsigned long long*)(ws + 239616);  // 131072 B
    unsigned long long* knns = (unsigned long long*)(ws + 370688);  // 1048576 B
    // total 1419264 B; poison-tagged slots need no zeroing (see slot_store).

    prep_kernel<<<64, 256, 0, stream>>>(xyz, w0, w1, w2, norms, W0T, W1T, W2c);
    // 8KB dynamic LDS -> per-block LDS 88576 B > 80KB -> 1 block/CU:
    // FPS blocks 0-3 get dedicated CUs (no spinner co-residency).
    mega_kernel<<<2820, 512, 8192, stream>>>(xyz, feat, norms, W0T, W1T, W2c,
                                             wwn, wnl0, wnl1, wnp,
                                             new_xyz, out2, nxs, invs, knns);
}